// Round 2
// baseline (1055.248 us; speedup 1.0000x reference)
//
#include <hip/hip_runtime.h>

#define FEAT 128

// ---------------- degree histogram ----------------
__global__ void k_count_deg(const int* __restrict__ ei, int E, int* __restrict__ deg) {
    int e = blockIdx.x * blockDim.x + threadIdx.x;
    if (e < E) atomicAdd(&deg[ei[E + e]], 1);
}

__global__ void k_dis(const int* __restrict__ deg, float* __restrict__ dis, int n) {
    int i = blockIdx.x * blockDim.x + threadIdx.x;
    if (i < n) dis[i] = rsqrtf((float)(1 + deg[i]));
}

// ---------------- single-block exclusive scan over deg -> row_ptr, cursor ----------------
__global__ void k_scan(const int* __restrict__ deg, int* __restrict__ row_ptr,
                       int* __restrict__ cursor, int n) {
    __shared__ int sums[1024];
    int tid = threadIdx.x;
    int chunk = (n + 1023) >> 10;
    int start = tid * chunk;
    int end = min(start + chunk, n);
    int s = 0;
    for (int i = start; i < end; ++i) s += deg[i];
    sums[tid] = s;
    __syncthreads();
    for (int off = 1; off < 1024; off <<= 1) {
        int v = (tid >= off) ? sums[tid - off] : 0;
        __syncthreads();
        sums[tid] += v;
        __syncthreads();
    }
    int run = (tid == 0) ? 0 : sums[tid - 1];
    for (int i = start; i < end; ++i) {
        row_ptr[i] = run;
        cursor[i] = run;
        run += deg[i];
    }
    if (tid == 1023) row_ptr[n] = sums[1023];
}

// ---------------- CSR fill ----------------
__global__ void k_fill_csr(const int* __restrict__ ei, int E,
                           const float* __restrict__ dis,
                           int* __restrict__ cursor,
                           int* __restrict__ csr_src, float* __restrict__ csr_norm) {
    int e = blockIdx.x * blockDim.x + threadIdx.x;
    if (e >= E) return;
    int s = ei[e], d = ei[E + e];
    int pos = atomicAdd(&cursor[d], 1);
    csr_src[pos] = s;
    csr_norm[pos] = dis[s] * dis[d];
}

// ---------------- GEMM: out[n,128] = A[n,128] @ W[128,128] ----------------
__global__ __launch_bounds__(256) void k_gemm128(const float* __restrict__ A,
                                                 const float* __restrict__ W,
                                                 float* __restrict__ out, int n) {
    __shared__ float As[32][33];   // transposed A chunk: As[k][row]
    __shared__ float Ws[32][128];
    int tid = threadIdx.x;
    int row0b = blockIdx.x * 32;
    int cg = tid & 31, rg = tid >> 5;
    int col0 = cg * 4, r0 = rg * 4;
    float acc[4][4] = {};
    int ar = tid >> 3;
    int ak = (tid & 7) * 4;
    int grow = row0b + ar;
    for (int kc = 0; kc < 128; kc += 32) {
        float4 v = make_float4(0.f, 0.f, 0.f, 0.f);
        if (grow < n) v = *(const float4*)(A + (size_t)grow * FEAT + kc + ak);
        As[ak + 0][ar] = v.x; As[ak + 1][ar] = v.y;
        As[ak + 2][ar] = v.z; As[ak + 3][ar] = v.w;
#pragma unroll
        for (int j = 0; j < 4; ++j) {
            int idx = tid + j * 256;       // 1024 float4 slots
            int wk = idx >> 5;
            int wc = (idx & 31) * 4;
            *(float4*)&Ws[wk][wc] = *(const float4*)(W + (size_t)(kc + wk) * 128 + wc);
        }
        __syncthreads();
#pragma unroll
        for (int k = 0; k < 32; ++k) {
            float a0 = As[k][r0 + 0], a1 = As[k][r0 + 1];
            float a2 = As[k][r0 + 2], a3 = As[k][r0 + 3];
            float4 w = *(float4*)&Ws[k][col0];
            acc[0][0] += a0 * w.x; acc[0][1] += a0 * w.y; acc[0][2] += a0 * w.z; acc[0][3] += a0 * w.w;
            acc[1][0] += a1 * w.x; acc[1][1] += a1 * w.y; acc[1][2] += a1 * w.z; acc[1][3] += a1 * w.w;
            acc[2][0] += a2 * w.x; acc[2][1] += a2 * w.y; acc[2][2] += a2 * w.z; acc[2][3] += a2 * w.w;
            acc[3][0] += a3 * w.x; acc[3][1] += a3 * w.y; acc[3][2] += a3 * w.z; acc[3][3] += a3 * w.w;
        }
        __syncthreads();
    }
#pragma unroll
    for (int i = 0; i < 4; ++i) {
        int row = row0b + r0 + i;
        if (row < n)
            *(float4*)(out + (size_t)row * 128 + col0) =
                make_float4(acc[i][0], acc[i][1], acc[i][2], acc[i][3]);
    }
}

// ---------------- head GEMM: mu = A@Wmu + bmu, ls = A@Wls + bls ----------------
__global__ __launch_bounds__(256) void k_gemm_head(const float* __restrict__ A,
                                                   const float* __restrict__ Wmu,
                                                   const float* __restrict__ Wls,
                                                   const float* __restrict__ bmu,
                                                   const float* __restrict__ bls,
                                                   float* __restrict__ mu,
                                                   float* __restrict__ ls, int n) {
    __shared__ float As[32][33];
    __shared__ float Ws[32][128];  // cols 0..63 = Wmu, 64..127 = Wls
    int tid = threadIdx.x;
    int row0b = blockIdx.x * 32;
    int cg = tid & 31, rg = tid >> 5;
    int col0 = cg * 4, r0 = rg * 4;
    float acc[4][4] = {};
    int ar = tid >> 3;
    int ak = (tid & 7) * 4;
    int grow = row0b + ar;
    for (int kc = 0; kc < 128; kc += 32) {
        float4 v = make_float4(0.f, 0.f, 0.f, 0.f);
        if (grow < n) v = *(const float4*)(A + (size_t)grow * FEAT + kc + ak);
        As[ak + 0][ar] = v.x; As[ak + 1][ar] = v.y;
        As[ak + 2][ar] = v.z; As[ak + 3][ar] = v.w;
#pragma unroll
        for (int j = 0; j < 4; ++j) {
            int idx = tid + j * 256;
            int wk = idx >> 5;
            int wc = (idx & 31) * 4;
            const float* Wp = (wc < 64) ? (Wmu + (size_t)(kc + wk) * 64 + wc)
                                        : (Wls + (size_t)(kc + wk) * 64 + (wc - 64));
            *(float4*)&Ws[wk][wc] = *(const float4*)Wp;
        }
        __syncthreads();
#pragma unroll
        for (int k = 0; k < 32; ++k) {
            float a0 = As[k][r0 + 0], a1 = As[k][r0 + 1];
            float a2 = As[k][r0 + 2], a3 = As[k][r0 + 3];
            float4 w = *(float4*)&Ws[k][col0];
            acc[0][0] += a0 * w.x; acc[0][1] += a0 * w.y; acc[0][2] += a0 * w.z; acc[0][3] += a0 * w.w;
            acc[1][0] += a1 * w.x; acc[1][1] += a1 * w.y; acc[1][2] += a1 * w.z; acc[1][3] += a1 * w.w;
            acc[2][0] += a2 * w.x; acc[2][1] += a2 * w.y; acc[2][2] += a2 * w.z; acc[2][3] += a2 * w.w;
            acc[3][0] += a3 * w.x; acc[3][1] += a3 * w.y; acc[3][2] += a3 * w.z; acc[3][3] += a3 * w.w;
        }
        __syncthreads();
    }
    bool is_mu = (col0 < 64);
    const float* bp = is_mu ? (bmu + col0) : (bls + (col0 - 64));
    float4 b = *(const float4*)bp;
    float* op = is_mu ? mu : ls;
    int c = is_mu ? col0 : col0 - 64;
#pragma unroll
    for (int i = 0; i < 4; ++i) {
        int row = row0b + r0 + i;
        if (row < n)
            *(float4*)(op + (size_t)row * 64 + c) =
                make_float4(acc[i][0] + b.x, acc[i][1] + b.y, acc[i][2] + b.z, acc[i][3] + b.w);
    }
}

// ---------------- aggregation: out = [relu](A_norm @ t + bias) ----------------
// wave per node; lane holds float2 of the 128 features
__global__ __launch_bounds__(256) void k_agg(const float* __restrict__ t,
                                             const int* __restrict__ row_ptr,
                                             const int* __restrict__ csr_src,
                                             const float* __restrict__ csr_norm,
                                             const float* __restrict__ dis,
                                             const float* __restrict__ bias,
                                             float* __restrict__ out, int n, int do_relu) {
    int wave = (int)((blockIdx.x * blockDim.x + threadIdx.x) >> 6);
    int lane = threadIdx.x & 63;
    if (wave >= n) return;
    int node = wave;
    float d = dis[node];
    float sw = d * d;
    float2 self = *(const float2*)(t + (size_t)node * FEAT + lane * 2);
    float2 acc0, acc1;
    acc0.x = self.x * sw; acc0.y = self.y * sw;
    acc1.x = 0.f; acc1.y = 0.f;
    int e = row_ptr[node], e1 = row_ptr[node + 1];
    for (; e + 1 < e1; e += 2) {
        int s0 = csr_src[e], s1 = csr_src[e + 1];
        float w0 = csr_norm[e], w1 = csr_norm[e + 1];
        float2 v0 = *(const float2*)(t + (size_t)s0 * FEAT + lane * 2);
        float2 v1 = *(const float2*)(t + (size_t)s1 * FEAT + lane * 2);
        acc0.x += w0 * v0.x; acc0.y += w0 * v0.y;
        acc1.x += w1 * v1.x; acc1.y += w1 * v1.y;
    }
    if (e < e1) {
        int s0 = csr_src[e];
        float w0 = csr_norm[e];
        float2 v0 = *(const float2*)(t + (size_t)s0 * FEAT + lane * 2);
        acc0.x += w0 * v0.x; acc0.y += w0 * v0.y;
    }
    acc0.x += acc1.x; acc0.y += acc1.y;
    if (bias) {
        acc0.x += bias[lane * 2];
        acc0.y += bias[lane * 2 + 1];
    }
    if (do_relu) {
        acc0.x = fmaxf(acc0.x, 0.f);
        acc0.y = fmaxf(acc0.y, 0.f);
    }
    *(float2*)(out + (size_t)node * FEAT + lane * 2) = acc0;
}

extern "C" void kernel_launch(void* const* d_in, const int* in_sizes, int n_in,
                              void* d_out, int out_size, void* d_ws, size_t ws_size,
                              hipStream_t stream) {
    const float* x   = (const float*)d_in[0];
    const int*   ei  = (const int*)d_in[1];
    const float* W1  = (const float*)d_in[2];
    const float* b1  = (const float*)d_in[3];
    const float* W2  = (const float*)d_in[4];
    const float* b2  = (const float*)d_in[5];
    const float* W3  = (const float*)d_in[6];
    const float* b3  = (const float*)d_in[7];
    const float* Wmu = (const float*)d_in[8];
    const float* bmu = (const float*)d_in[9];
    const float* Wls = (const float*)d_in[10];
    const float* bls = (const float*)d_in[11];

    int n = in_sizes[0] / FEAT;    // 50000
    int E = in_sizes[1] / 2;       // 1,600,000

    char* ws = (char*)d_ws;
    size_t off = 0;
    auto alloc = [&](size_t bytes) {
        void* p = ws + off;
        off = (off + bytes + 255) & ~(size_t)255;
        return p;
    };
    float* Bt       = (float*)alloc((size_t)n * FEAT * 4);
    float* Bh       = (float*)alloc((size_t)n * FEAT * 4);
    int*   deg      = (int*)alloc((size_t)n * 4);
    float* dis      = (float*)alloc((size_t)n * 4);
    int*   row_ptr  = (int*)alloc((size_t)(n + 1) * 4);
    int*   cursor   = (int*)alloc((size_t)n * 4);
    int*   csr_src  = (int*)alloc((size_t)E * 4);
    float* csr_norm = (float*)alloc((size_t)E * 4);

    hipMemsetAsync(deg, 0, (size_t)n * 4, stream);

    int eb = (E + 255) / 256;
    k_count_deg<<<eb, 256, 0, stream>>>(ei, E, deg);
    k_dis<<<(n + 255) / 256, 256, 0, stream>>>(deg, dis, n);
    k_scan<<<1, 1024, 0, stream>>>(deg, row_ptr, cursor, n);
    k_fill_csr<<<eb, 256, 0, stream>>>(ei, E, dis, cursor, csr_src, csr_norm);

    int gb = (n + 31) / 32;
    int ab = (n + 3) / 4;
    float* mu = (float*)d_out;
    float* ls = (float*)d_out + (size_t)n * 64;

    k_gemm128<<<gb, 256, 0, stream>>>(x,  W1, Bt, n);
    k_agg<<<ab, 256, 0, stream>>>(Bt, row_ptr, csr_src, csr_norm, dis, b1, Bh, n, 1);
    k_gemm128<<<gb, 256, 0, stream>>>(Bh, W2, Bt, n);
    k_agg<<<ab, 256, 0, stream>>>(Bt, row_ptr, csr_src, csr_norm, dis, b2, Bh, n, 1);
    k_gemm128<<<gb, 256, 0, stream>>>(Bh, W3, Bt, n);
    k_agg<<<ab, 256, 0, stream>>>(Bt, row_ptr, csr_src, csr_norm, dis, b3, Bh, n, 1);
    // g = A_norm @ h3 (shared by both heads; aggregation is linear)
    k_agg<<<ab, 256, 0, stream>>>(Bh, row_ptr, csr_src, csr_norm, dis, nullptr, Bt, n, 0);
    k_gemm_head<<<gb, 256, 0, stream>>>(Bt, Wmu, Wls, bmu, bls, mu, ls, n);
}